// Round 1
// baseline (402.893 us; speedup 1.0000x reference)
//
#include <hip/hip_runtime.h>
#include <math.h>

// EfficientAttention: x[2,64,64,64,64] fp32, H=4 heads, dk=16.
//   k,v,q = per-token 64x64 projections; ctx_h = softmax_N(k_h) @ v_h^T (16x16);
//   out = Wr @ (ctx^T @ softmax_dk(q)) + br, folded as out = M @ qhat + br with
//   M[c][h*16+kc] = sum_vc Wr[c][h*16+vc] * ctx_h[kc][vc].

#define NTOK 262144   // 64*64*64 tokens per batch
#define PAD  68       // padded row stride for [64][PAD] LDS tiles (16B-aligned rows)

typedef float4 f4;

// ---- workspace float offsets ----
#define WS_S    0        // 2048 : S[n][h][kc][vc]
#define WS_Z    2048     // 128  : Z[n][h*16+kc]
#define WS_M    2176     // 8192 : M[n][p][c], p = h*16+kc
#define WS_WKT  10368    // 4096 : WkT[j][c]
#define WS_WVT  14464    // 4096
#define WS_WQT  18560    // 4096
// total 22656 floats = 90.6 KB

__global__ __launch_bounds__(256) void k_init(const float* __restrict__ Wk,
                                              const float* __restrict__ Wv,
                                              const float* __restrict__ Wq,
                                              float* __restrict__ ws) {
    int i = blockIdx.x * 256 + threadIdx.x;   // grid 16 -> i in [0,4096)
    if (i < 2176) ws[i] = 0.0f;               // zero S and Z
    if (i < 4096) {
        int c = i & 63, j = i >> 6;           // i = j*64 + c
        ws[WS_WKT + i] = Wk[c * 64 + j];
        ws[WS_WVT + i] = Wv[c * 64 + j];
        ws[WS_WQT + i] = Wq[c * 64 + j];
    }
}

// ---------------- Pass 1: k,v projection + ctx accumulation ----------------
__global__ __launch_bounds__(256) void k_ctx(const float* __restrict__ x,
                                             const float* __restrict__ bk,
                                             const float* __restrict__ bv,
                                             float* __restrict__ ws) {
    __shared__ float bufA[64][PAD];   // xT[j][t], then ek[c][t]
    __shared__ float bufB[64][PAD];   // ev[c][t]

    const int tid  = threadIdx.x;
    const int w    = tid >> 6;            // wave = head in phase C
    const int lane = tid & 63;
    // phase B mapping: thread = (cg, tg) computing c in [4cg,4cg+4) x t in [4tg,4tg+4)
    const int tg = tid & 15;
    const int cl = (tid >> 4) & 3;
    const int cg = w * 4 + cl;
    const int c0 = cg * 4;
    const int t0 = tg * 4;
    // staging mapping
    const int sj4 = tid & 15;
    const int st4 = tid >> 4;
    // phase C mapping
    const int tq  = lane >> 4;
    const int kc4 = (lane >> 2) & 3;
    const int vq  = lane & 3;

    const int nb = blockIdx.x >> 9;       // batch
    const int bi = blockIdx.x & 511;

    const float* WkT = ws + WS_WKT;
    const float* WvT = ws + WS_WVT;

    const f4 bk4 = *(const f4*)&bk[c0];
    const f4 bv4 = *(const f4*)&bv[c0];
    const float bks[4] = {bk4.x, bk4.y, bk4.z, bk4.w};
    const float bvs[4] = {bv4.x, bv4.y, bv4.z, bv4.w};

    float S[4][4];    // S[kc4+4i][vq+4u] partials
    float z[4];
    #pragma unroll
    for (int i = 0; i < 4; ++i) {
        z[i] = 0.f;
        #pragma unroll
        for (int u = 0; u < 4; ++u) S[i][u] = 0.f;
    }

    for (int s = 0; s < 8; ++s) {
        const int tile = bi + s * 512;
        const int base = nb * NTOK + tile * 64;
        __syncthreads();   // previous phase C done before overwriting buffers
        {
            const f4 r0 = *(const f4*)&x[(base + st4 * 4 + 0) * 64 + sj4 * 4];
            const f4 r1 = *(const f4*)&x[(base + st4 * 4 + 1) * 64 + sj4 * 4];
            const f4 r2 = *(const f4*)&x[(base + st4 * 4 + 2) * 64 + sj4 * 4];
            const f4 r3 = *(const f4*)&x[(base + st4 * 4 + 3) * 64 + sj4 * 4];
            *(f4*)&bufA[sj4 * 4 + 0][st4 * 4] = make_float4(r0.x, r1.x, r2.x, r3.x);
            *(f4*)&bufA[sj4 * 4 + 1][st4 * 4] = make_float4(r0.y, r1.y, r2.y, r3.y);
            *(f4*)&bufA[sj4 * 4 + 2][st4 * 4] = make_float4(r0.z, r1.z, r2.z, r3.z);
            *(f4*)&bufA[sj4 * 4 + 3][st4 * 4] = make_float4(r0.w, r1.w, r2.w, r3.w);
        }
        __syncthreads();
        // phase B: k,v projection with 4x4 register tile
        float ak[4][4], av[4][4];
        #pragma unroll
        for (int u = 0; u < 4; ++u)
            #pragma unroll
            for (int t = 0; t < 4; ++t) { ak[u][t] = 0.f; av[u][t] = 0.f; }
        #pragma unroll 4
        for (int j = 0; j < 64; ++j) {
            const f4 xv = *(const f4*)&bufA[j][t0];
            const f4 wk = *(const f4*)&WkT[(j << 6) + c0];
            const f4 wv = *(const f4*)&WvT[(j << 6) + c0];
            const float xs[4]  = {xv.x, xv.y, xv.z, xv.w};
            const float wks[4] = {wk.x, wk.y, wk.z, wk.w};
            const float wvs[4] = {wv.x, wv.y, wv.z, wv.w};
            #pragma unroll
            for (int u = 0; u < 4; ++u)
                #pragma unroll
                for (int t = 0; t < 4; ++t) {
                    ak[u][t] = fmaf(wks[u], xs[t], ak[u][t]);
                    av[u][t] = fmaf(wvs[u], xs[t], av[u][t]);
                }
        }
        float ek[4][4], ev[4][4];
        #pragma unroll
        for (int u = 0; u < 4; ++u)
            #pragma unroll
            for (int t = 0; t < 4; ++t) {
                ek[u][t] = __expf(ak[u][t] + bks[u]);
                ev[u][t] = av[u][t] + bvs[u];
            }
        __syncthreads();   // all xT reads done; reuse bufA for ek
        #pragma unroll
        for (int u = 0; u < 4; ++u) {
            *(f4*)&bufA[c0 + u][t0] = make_float4(ek[u][0], ek[u][1], ek[u][2], ek[u][3]);
            *(f4*)&bufB[c0 + u][t0] = make_float4(ev[u][0], ev[u][1], ev[u][2], ev[u][3]);
        }
        __syncthreads();
        // phase C: per-wave head w, outer-product accumulation over tile tokens
        #pragma unroll
        for (int t4 = 0; t4 < 4; ++t4) {
            const int t = tq * 16 + t4 * 4;
            float es[4][4], vs[4][4];
            #pragma unroll
            for (int i = 0; i < 4; ++i) {
                const f4 e = *(const f4*)&bufA[(w << 4) + kc4 + (i << 2)][t];
                es[i][0] = e.x; es[i][1] = e.y; es[i][2] = e.z; es[i][3] = e.w;
            }
            #pragma unroll
            for (int u = 0; u < 4; ++u) {
                const f4 vv = *(const f4*)&bufB[(w << 4) + vq + (u << 2)][t];
                vs[u][0] = vv.x; vs[u][1] = vv.y; vs[u][2] = vv.z; vs[u][3] = vv.w;
            }
            #pragma unroll
            for (int i = 0; i < 4; ++i) {
                z[i] += es[i][0] + es[i][1] + es[i][2] + es[i][3];
                #pragma unroll
                for (int u = 0; u < 4; ++u)
                    #pragma unroll
                    for (int tt = 0; tt < 4; ++tt)
                        S[i][u] = fmaf(es[i][tt], vs[u][tt], S[i][u]);
            }
        }
    }
    // reduce partials across tq lane groups, then atomics
    #pragma unroll
    for (int i = 0; i < 4; ++i) {
        #pragma unroll
        for (int u = 0; u < 4; ++u) {
            float v = S[i][u];
            v += __shfl_xor(v, 16);
            v += __shfl_xor(v, 32);
            S[i][u] = v;
        }
        float zv = z[i];
        zv += __shfl_xor(zv, 16);
        zv += __shfl_xor(zv, 32);
        z[i] = zv;
    }
    if (tq == 0) {
        #pragma unroll
        for (int i = 0; i < 4; ++i) {
            const int kc = kc4 + 4 * i;
            #pragma unroll
            for (int u = 0; u < 4; ++u) {
                const int vc = vq + 4 * u;
                atomicAdd(&ws[WS_S + nb * 1024 + w * 256 + kc * 16 + vc], S[i][u]);
            }
            if (vq == 0) atomicAdd(&ws[WS_Z + nb * 64 + w * 16 + kc], z[i]);
        }
    }
}

// ---------------- M = Wr @ (S/Z) fold ----------------
__global__ __launch_bounds__(256) void k_m(const float* __restrict__ Wr,
                                           float* __restrict__ ws) {
    const int n = blockIdx.x;
    for (int i = threadIdx.x; i < 4096; i += 256) {
        const int p = i >> 6, c = i & 63;
        const int h = p >> 4, kc = p & 15;
        const float rz = 1.0f / ws[WS_Z + n * 64 + p];
        const float* Srow = ws + WS_S + n * 1024 + h * 256 + kc * 16;
        const float* Wrow = Wr + c * 64 + h * 16;
        float acc = 0.f;
        #pragma unroll
        for (int vc = 0; vc < 16; ++vc) acc += Wrow[vc] * Srow[vc];
        ws[WS_M + n * 4096 + p * 64 + c] = acc * rz;
    }
}

// ---------------- Pass 2: q projection + softmax + M apply ----------------
__global__ __launch_bounds__(256) void k_out(const float* __restrict__ x,
                                             const float* __restrict__ bq,
                                             const float* __restrict__ br,
                                             float* __restrict__ out,
                                             const float* __restrict__ ws) {
    __shared__ float bufA[64][PAD];   // xT[j][t], then qhat[p][t]

    const int tid = threadIdx.x;
    const int w   = tid >> 6;
    const int tg  = tid & 15;
    const int cl  = (tid >> 4) & 3;
    const int cg  = w * 4 + cl;
    const int c0  = cg * 4;
    const int t0  = tg * 4;
    const int sj4 = tid & 15;
    const int st4 = tid >> 4;

    const int nb = blockIdx.x >> 10;
    const int bi = blockIdx.x & 1023;

    const float* WqT = ws + WS_WQT;
    const float* Mb  = ws + WS_M + nb * 4096;

    const f4 bq4 = *(const f4*)&bq[c0];
    const f4 br4 = *(const f4*)&br[c0];
    const float bqs[4] = {bq4.x, bq4.y, bq4.z, bq4.w};
    const float brs[4] = {br4.x, br4.y, br4.z, br4.w};

    for (int s = 0; s < 4; ++s) {
        const int tile = bi + s * 1024;
        const int base = nb * NTOK + tile * 64;
        __syncthreads();
        {
            const f4 r0 = *(const f4*)&x[(base + st4 * 4 + 0) * 64 + sj4 * 4];
            const f4 r1 = *(const f4*)&x[(base + st4 * 4 + 1) * 64 + sj4 * 4];
            const f4 r2 = *(const f4*)&x[(base + st4 * 4 + 2) * 64 + sj4 * 4];
            const f4 r3 = *(const f4*)&x[(base + st4 * 4 + 3) * 64 + sj4 * 4];
            *(f4*)&bufA[sj4 * 4 + 0][st4 * 4] = make_float4(r0.x, r1.x, r2.x, r3.x);
            *(f4*)&bufA[sj4 * 4 + 1][st4 * 4] = make_float4(r0.y, r1.y, r2.y, r3.y);
            *(f4*)&bufA[sj4 * 4 + 2][st4 * 4] = make_float4(r0.z, r1.z, r2.z, r3.z);
            *(f4*)&bufA[sj4 * 4 + 3][st4 * 4] = make_float4(r0.w, r1.w, r2.w, r3.w);
        }
        __syncthreads();
        float aq[4][4];
        #pragma unroll
        for (int u = 0; u < 4; ++u)
            #pragma unroll
            for (int t = 0; t < 4; ++t) aq[u][t] = 0.f;
        #pragma unroll 4
        for (int j = 0; j < 64; ++j) {
            const f4 xv = *(const f4*)&bufA[j][t0];
            const f4 wq = *(const f4*)&WqT[(j << 6) + c0];
            const float xs[4]  = {xv.x, xv.y, xv.z, xv.w};
            const float wqs[4] = {wq.x, wq.y, wq.z, wq.w};
            #pragma unroll
            for (int u = 0; u < 4; ++u)
                #pragma unroll
                for (int t = 0; t < 4; ++t)
                    aq[u][t] = fmaf(wqs[u], xs[t], aq[u][t]);
        }
        // per-token softmax over the head's 16 channels (this wave = head w's
        // channels live on lanes lane^16, lane^32 relative to this one)
        float qh[4][4];
        #pragma unroll
        for (int t = 0; t < 4; ++t) {
            float q0 = aq[0][t] + bqs[0];
            float q1 = aq[1][t] + bqs[1];
            float q2 = aq[2][t] + bqs[2];
            float q3 = aq[3][t] + bqs[3];
            float m = fmaxf(fmaxf(q0, q1), fmaxf(q2, q3));
            m = fmaxf(m, __shfl_xor(m, 16));
            m = fmaxf(m, __shfl_xor(m, 32));
            float e0 = __expf(q0 - m), e1 = __expf(q1 - m);
            float e2 = __expf(q2 - m), e3 = __expf(q3 - m);
            float ssum = e0 + e1 + e2 + e3;
            ssum += __shfl_xor(ssum, 16);
            ssum += __shfl_xor(ssum, 32);
            const float r = 1.0f / ssum;
            qh[0][t] = e0 * r; qh[1][t] = e1 * r;
            qh[2][t] = e2 * r; qh[3][t] = e3 * r;
        }
        __syncthreads();   // xT reads done; reuse bufA for qhat
        #pragma unroll
        for (int u = 0; u < 4; ++u)
            *(f4*)&bufA[c0 + u][t0] = make_float4(qh[u][0], qh[u][1], qh[u][2], qh[u][3]);
        __syncthreads();
        // out = M @ qhat + br
        float o[4][4];
        #pragma unroll
        for (int u = 0; u < 4; ++u)
            #pragma unroll
            for (int t = 0; t < 4; ++t) o[u][t] = 0.f;
        #pragma unroll 4
        for (int p = 0; p < 64; ++p) {
            const f4 m4 = *(const f4*)&Mb[(p << 6) + c0];
            const f4 qv = *(const f4*)&bufA[p][t0];
            const float ms[4] = {m4.x, m4.y, m4.z, m4.w};
            const float qs[4] = {qv.x, qv.y, qv.z, qv.w};
            #pragma unroll
            for (int u = 0; u < 4; ++u)
                #pragma unroll
                for (int t = 0; t < 4; ++t)
                    o[u][t] = fmaf(ms[u], qs[t], o[u][t]);
        }
        #pragma unroll
        for (int t = 0; t < 4; ++t) {
            const f4 o4 = make_float4(o[0][t] + brs[0], o[1][t] + brs[1],
                                      o[2][t] + brs[2], o[3][t] + brs[3]);
            *(f4*)&out[(base + t0 + t) * 64 + c0] = o4;
        }
    }
}

extern "C" void kernel_launch(void* const* d_in, const int* in_sizes, int n_in,
                              void* d_out, int out_size, void* d_ws, size_t ws_size,
                              hipStream_t stream) {
    const float* x  = (const float*)d_in[0];
    const float* Wk = (const float*)d_in[1];
    const float* bk = (const float*)d_in[2];
    const float* Wq = (const float*)d_in[3];
    const float* bq = (const float*)d_in[4];
    const float* Wv = (const float*)d_in[5];
    const float* bv = (const float*)d_in[6];
    const float* Wr = (const float*)d_in[7];
    const float* br = (const float*)d_in[8];
    float* out = (float*)d_out;
    float* ws  = (float*)d_ws;

    hipLaunchKernelGGL(k_init, dim3(16),   dim3(256), 0, stream, Wk, Wv, Wq, ws);
    hipLaunchKernelGGL(k_ctx,  dim3(1024), dim3(256), 0, stream, x, bk, bv, ws);
    hipLaunchKernelGGL(k_m,    dim3(2),    dim3(256), 0, stream, Wr, ws);
    hipLaunchKernelGGL(k_out,  dim3(2048), dim3(256), 0, stream, x, bq, br, out, ws);
}

// Round 2
// 176.930 us; speedup vs baseline: 2.2771x; 2.2771x over previous
//
#include <hip/hip_runtime.h>
#include <math.h>

// EfficientAttention, MFMA version.
//   ctx_h = softmax_N(k_h) @ v_h^T folded with Wr into M[n][oc][p] (p=h*16+kc):
//   out = M @ softmax_dk(q) + br.
// Pass 1: plain bf16 MFMA (errors average over N=262144 tokens).
// Pass 2: 3-term hi/lo bf16 split MFMA (~fp32 accuracy, per-token sensitive).

#define NTOK 262144
typedef float4 f4;
typedef __attribute__((ext_vector_type(8))) short bf16x8;
typedef __attribute__((ext_vector_type(4))) float f32x4;

// ---- workspace float offsets ----
#define WS_S 0      // 2048 : S[n][h][kc][vc]
#define WS_Z 2048   // 128  : Z[n][h*16+kc]
#define WS_M 2176   // 8192 : M[n][c][p]

__device__ __forceinline__ ushort f2bf(float f) {
    union { float f; unsigned u; } c; c.f = f;
    unsigned r = c.u + 0x7FFFu + ((c.u >> 16) & 1u);   // RNE
    return (ushort)(r >> 16);
}
__device__ __forceinline__ float bf2f(ushort h) {
    union { unsigned u; float f; } c; c.u = ((unsigned)h) << 16;
    return c.f;
}
__device__ __forceinline__ bf16x8 cvt8(const float* v) {
    bf16x8 r;
    #pragma unroll
    for (int m = 0; m < 8; ++m) r[m] = (short)f2bf(v[m]);
    return r;
}
__device__ __forceinline__ void cvt_hilo(const float* v, bf16x8& hi, bf16x8& lo) {
    #pragma unroll
    for (int m = 0; m < 8; ++m) {
        ushort h = f2bf(v[m]);
        hi[m] = (short)h;
        lo[m] = (short)f2bf(v[m] - bf2f(h));
    }
}

__global__ __launch_bounds__(256) void k_init(float* __restrict__ ws) {
    int i = blockIdx.x * 256 + threadIdx.x;
    if (i < 2176) ws[i] = 0.0f;   // zero S and Z
}

// ---------------- Pass 1: k,v projection + ctx accumulation ----------------
// Wave w = head w. Per 16-token subtile: A-frag = x rows (token=lane&15,
// j=8*(lane>>4)+m+32jc), B-frag = Wk/Wv rows (c=16w+(lane&15), same j) ->
// D_k[t][c]: lane holds col c=lane&15, rows t=4*(lane>>4)+r.
// Phase C per 32-token chunk: S += EK^T(16x32) x EV(32x16) via LDS repack.
__global__ __launch_bounds__(256) void k_ctx(const float* __restrict__ x,
                                             const float* __restrict__ Wk,
                                             const float* __restrict__ bk,
                                             const float* __restrict__ Wv,
                                             const float* __restrict__ bv,
                                             float* __restrict__ ws) {
    __shared__ ushort ekb[4][16][40];   // per-wave [c][t] bf16, stride 40 (16B-aligned rows)
    __shared__ ushort evb[4][16][40];

    const int tid  = threadIdx.x;
    const int w    = tid >> 6;
    const int lane = tid & 63;
    const int lr   = lane & 15;
    const int ql   = lane >> 4;

    const int nb = blockIdx.x >> 9;
    const int bi = blockIdx.x & 511;
    const long base = (long)nb * NTOK + (long)bi * 512;

    // W B-frags (bf16, register-resident): lane holds c=16w+lr, k=j=32jc+8ql+m
    bf16x8 wkf[2], wvf[2];
    {
        const float* wkrow = &Wk[(16 * w + lr) * 64 + 8 * ql];
        const float* wvrow = &Wv[(16 * w + lr) * 64 + 8 * ql];
        float t[8];
        #pragma unroll
        for (int jc = 0; jc < 2; ++jc) {
            *(f4*)&t[0] = *(const f4*)&wkrow[32 * jc];
            *(f4*)&t[4] = *(const f4*)&wkrow[32 * jc + 4];
            wkf[jc] = cvt8(t);
            *(f4*)&t[0] = *(const f4*)&wvrow[32 * jc];
            *(f4*)&t[4] = *(const f4*)&wvrow[32 * jc + 4];
            wvf[jc] = cvt8(t);
        }
    }
    const float bks = bk[16 * w + lr];
    const float bvs = bv[16 * w + lr];

    const f32x4 zero4 = {0.f, 0.f, 0.f, 0.f};
    f32x4 S = zero4;
    float z = 0.f;

    for (int ch = 0; ch < 16; ++ch) {
        #pragma unroll
        for (int s = 0; s < 2; ++s) {
            const float* xp = x + (((size_t)(base + ch * 32 + s * 16 + lr)) << 6) + 8 * ql;
            float t0[8], t1[8];
            *(f4*)&t0[0] = *(const f4*)(xp);
            *(f4*)&t0[4] = *(const f4*)(xp + 4);
            *(f4*)&t1[0] = *(const f4*)(xp + 32);
            *(f4*)&t1[4] = *(const f4*)(xp + 36);
            bf16x8 a0 = cvt8(t0), a1 = cvt8(t1);
            f32x4 ak = zero4, av = zero4;
            ak = __builtin_amdgcn_mfma_f32_16x16x32_bf16(a0, wkf[0], ak, 0, 0, 0);
            ak = __builtin_amdgcn_mfma_f32_16x16x32_bf16(a1, wkf[1], ak, 0, 0, 0);
            av = __builtin_amdgcn_mfma_f32_16x16x32_bf16(a0, wvf[0], av, 0, 0, 0);
            av = __builtin_amdgcn_mfma_f32_16x16x32_bf16(a1, wvf[1], av, 0, 0, 0);
            const float e0 = __expf(ak[0] + bks), e1 = __expf(ak[1] + bks);
            const float e2 = __expf(ak[2] + bks), e3 = __expf(ak[3] + bks);
            z += (e0 + e1) + (e2 + e3);
            const float v0 = av[0] + bvs, v1 = av[1] + bvs;
            const float v2 = av[2] + bvs, v3 = av[3] + bvs;
            uint2 pk, pv;
            pk.x = (uint)f2bf(e0) | ((uint)f2bf(e1) << 16);
            pk.y = (uint)f2bf(e2) | ((uint)f2bf(e3) << 16);
            pv.x = (uint)f2bf(v0) | ((uint)f2bf(v1) << 16);
            pv.y = (uint)f2bf(v2) | ((uint)f2bf(v3) << 16);
            *(uint2*)&ekb[w][lr][s * 16 + 4 * ql] = pk;   // [c=lr][t=16s+4ql..+3]
            *(uint2*)&evb[w][lr][s * 16 + 4 * ql] = pv;
        }
        // phase C: A = EK^T (row kc=lr, k=t=8ql+m), B = EV (col vc=lr, same t)
        bf16x8 ekf = *(bf16x8*)&ekb[w][lr][8 * ql];
        bf16x8 evf = *(bf16x8*)&evb[w][lr][8 * ql];
        S = __builtin_amdgcn_mfma_f32_16x16x32_bf16(ekf, evf, S, 0, 0, 0);
    }

    // z: sum over quartiles (same kc=lr lives on lanes lr, lr+16, lr+32, lr+48)
    z += __shfl_xor(z, 16);
    z += __shfl_xor(z, 32);
    // S D-layout: col vc=lr, row kc=4ql+r
    float* Sp = ws + WS_S + nb * 1024 + w * 256;
    #pragma unroll
    for (int r = 0; r < 4; ++r)
        atomicAdd(&Sp[(4 * ql + r) * 16 + lr], S[r]);
    if (lane < 16)
        atomicAdd(&ws[WS_Z + nb * 64 + w * 16 + lane], z);
}

// ---------------- M = Wr @ (S/Z) fold : M[n][c][p] ----------------
__global__ __launch_bounds__(256) void k_m(const float* __restrict__ Wr,
                                           float* __restrict__ ws) {
    const int n = blockIdx.x;
    for (int i = threadIdx.x; i < 4096; i += 256) {
        const int c = i >> 6, p = i & 63;
        const int h = p >> 4, kc = p & 15;
        const float rz = 1.0f / ws[WS_Z + n * 64 + p];
        const float* Srow = ws + WS_S + n * 1024 + h * 256 + kc * 16;
        const float* Wrow = Wr + c * 64 + h * 16;
        float acc = 0.f;
        #pragma unroll
        for (int vc = 0; vc < 16; ++vc) acc += Wrow[vc] * Srow[vc];
        ws[WS_M + n * 4096 + c * 64 + p] = acc * rz;
    }
}

// ---------------- Pass 2: q proj + softmax + M apply (hi/lo split) ----------
// Wave w = head w for q, oc-tile w for out. 128 tokens/block, 8 subtiles.
// Phase A: D_q[c][t] = Wq(A) x X^T(B); softmax over c (regs + shfl 16/32);
//          qhat hi/lo -> LDS [t][p] (stride 72, XOR-swizzled by (row&3)<<4).
// Phase B: D_out[oc][t] = M(A) x qhat(B), 3-term split, + br, store.
__global__ __launch_bounds__(256) void k_out(const float* __restrict__ x,
                                             const float* __restrict__ Wq,
                                             const float* __restrict__ bq,
                                             const float* __restrict__ br,
                                             float* __restrict__ out,
                                             const float* __restrict__ ws) {
    __shared__ ushort qh_h[128][72];
    __shared__ ushort qh_l[128][72];

    const int tid  = threadIdx.x;
    const int w    = tid >> 6;
    const int lane = tid & 63;
    const int lr   = lane & 15;
    const int ql   = lane >> 4;

    const int nb = blockIdx.x >> 11;
    const int bi = blockIdx.x & 2047;
    const long base = (long)nb * NTOK + (long)bi * 128;

    // Wq A-frags hi/lo: lane row c(within head)=lr -> Wq[16w+lr][32jc+8ql+m]
    bf16x8 wqh[2], wql[2];
    {
        const float* wr = &Wq[(16 * w + lr) * 64 + 8 * ql];
        float t[8];
        #pragma unroll
        for (int jc = 0; jc < 2; ++jc) {
            *(f4*)&t[0] = *(const f4*)&wr[32 * jc];
            *(f4*)&t[4] = *(const f4*)&wr[32 * jc + 4];
            cvt_hilo(t, wqh[jc], wql[jc]);
        }
    }
    // M A-frags hi/lo: lane row oc=16w+lr, k=p=32pc+8ql+m
    bf16x8 mh[2], ml[2];
    {
        const float* mrow = ws + WS_M + nb * 4096 + (16 * w + lr) * 64 + 8 * ql;
        float t[8];
        #pragma unroll
        for (int pc = 0; pc < 2; ++pc) {
            *(f4*)&t[0] = *(const f4*)&mrow[32 * pc];
            *(f4*)&t[4] = *(const f4*)&mrow[32 * pc + 4];
            cvt_hilo(t, mh[pc], ml[pc]);
        }
    }
    const f4 bq4 = *(const f4*)&bq[16 * w + 4 * ql];
    const f4 br4 = *(const f4*)&br[16 * w + 4 * ql];
    const f32x4 zero4 = {0.f, 0.f, 0.f, 0.f};

    // ---- phase A ----
    for (int s = 0; s < 8; ++s) {
        const float* xp = x + (((size_t)(base + s * 16 + lr)) << 6) + 8 * ql;
        float t0[8], t1[8];
        *(f4*)&t0[0] = *(const f4*)(xp);
        *(f4*)&t0[4] = *(const f4*)(xp + 4);
        *(f4*)&t1[0] = *(const f4*)(xp + 32);
        *(f4*)&t1[4] = *(const f4*)(xp + 36);
        bf16x8 b0h, b0l, b1h, b1l;
        cvt_hilo(t0, b0h, b0l);
        cvt_hilo(t1, b1h, b1l);
        f32x4 aq = zero4;
        aq = __builtin_amdgcn_mfma_f32_16x16x32_bf16(wqh[0], b0h, aq, 0, 0, 0);
        aq = __builtin_amdgcn_mfma_f32_16x16x32_bf16(wql[0], b0h, aq, 0, 0, 0);
        aq = __builtin_amdgcn_mfma_f32_16x16x32_bf16(wqh[0], b0l, aq, 0, 0, 0);
        aq = __builtin_amdgcn_mfma_f32_16x16x32_bf16(wqh[1], b1h, aq, 0, 0, 0);
        aq = __builtin_amdgcn_mfma_f32_16x16x32_bf16(wql[1], b1h, aq, 0, 0, 0);
        aq = __builtin_amdgcn_mfma_f32_16x16x32_bf16(wqh[1], b1l, aq, 0, 0, 0);
        // softmax over head channels c = 4ql+r (regs) x quartiles (shfl)
        float q0 = aq[0] + bq4.x, q1 = aq[1] + bq4.y;
        float q2 = aq[2] + bq4.z, q3 = aq[3] + bq4.w;
        float mx = fmaxf(fmaxf(q0, q1), fmaxf(q2, q3));
        mx = fmaxf(mx, __shfl_xor(mx, 16));
        mx = fmaxf(mx, __shfl_xor(mx, 32));
        float e0 = __expf(q0 - mx), e1 = __expf(q1 - mx);
        float e2 = __expf(q2 - mx), e3 = __expf(q3 - mx);
        float sm = (e0 + e1) + (e2 + e3);
        sm += __shfl_xor(sm, 16);
        sm += __shfl_xor(sm, 32);
        const float rs = 1.0f / sm;
        const float h0 = e0 * rs, h1 = e1 * rs, h2 = e2 * rs, h3 = e3 * rs;
        // hi/lo split + swizzled write: row = token, realcol p = 16w+4ql+r
        const int row = s * 16 + lr;
        const int cb  = (16 * (w ^ (row & 3))) + 4 * ql;
        ushort a0 = f2bf(h0), a1 = f2bf(h1), a2 = f2bf(h2), a3 = f2bf(h3);
        ushort l0 = f2bf(h0 - bf2f(a0)), l1 = f2bf(h1 - bf2f(a1));
        ushort l2 = f2bf(h2 - bf2f(a2)), l3 = f2bf(h3 - bf2f(a3));
        uint2 ph, pl;
        ph.x = (uint)a0 | ((uint)a1 << 16);
        ph.y = (uint)a2 | ((uint)a3 << 16);
        pl.x = (uint)l0 | ((uint)l1 << 16);
        pl.y = (uint)l2 | ((uint)l3 << 16);
        *(uint2*)&qh_h[row][cb] = ph;
        *(uint2*)&qh_l[row][cb] = pl;
    }
    __syncthreads();
    // ---- phase B ----
    for (int s = 0; s < 8; ++s) {
        const int row = s * 16 + lr;                 // token = col t of D_out
        f32x4 o = zero4;
        #pragma unroll
        for (int pc = 0; pc < 2; ++pc) {
            const int cb = (32 * pc + 8 * ql) ^ ((row & 3) << 4);
            bf16x8 qhv = *(bf16x8*)&qh_h[row][cb];
            bf16x8 qlv = *(bf16x8*)&qh_l[row][cb];
            o = __builtin_amdgcn_mfma_f32_16x16x32_bf16(mh[pc], qhv, o, 0, 0, 0);
            o = __builtin_amdgcn_mfma_f32_16x16x32_bf16(ml[pc], qhv, o, 0, 0, 0);
            o = __builtin_amdgcn_mfma_f32_16x16x32_bf16(mh[pc], qlv, o, 0, 0, 0);
        }
        const f4 res = {o[0] + br4.x, o[1] + br4.y, o[2] + br4.z, o[3] + br4.w};
        *(f4*)&out[(((size_t)(base + s * 16 + lr)) << 6) + 16 * w + 4 * ql] = res;
    }
}

extern "C" void kernel_launch(void* const* d_in, const int* in_sizes, int n_in,
                              void* d_out, int out_size, void* d_ws, size_t ws_size,
                              hipStream_t stream) {
    const float* x  = (const float*)d_in[0];
    const float* Wk = (const float*)d_in[1];
    const float* bk = (const float*)d_in[2];
    const float* Wq = (const float*)d_in[3];
    const float* bq = (const float*)d_in[4];
    const float* Wv = (const float*)d_in[5];
    const float* bv = (const float*)d_in[6];
    const float* Wr = (const float*)d_in[7];
    const float* br = (const float*)d_in[8];
    float* out = (float*)d_out;
    float* ws  = (float*)d_ws;

    hipLaunchKernelGGL(k_init, dim3(9),    dim3(256), 0, stream, ws);
    hipLaunchKernelGGL(k_ctx,  dim3(1024), dim3(256), 0, stream, x, Wk, bk, Wv, bv, ws);
    hipLaunchKernelGGL(k_m,    dim3(2),    dim3(256), 0, stream, Wr, ws);
    hipLaunchKernelGGL(k_out,  dim3(4096), dim3(256), 0, stream, x, Wq, bq, br, out, ws);
}

// Round 3
// 166.332 us; speedup vs baseline: 2.4222x; 1.0637x over previous
//
#include <hip/hip_runtime.h>
#include <math.h>

// EfficientAttention, fp16-MFMA version.
//   ctx_h = softmax_N(k_h) @ v_h^T folded with Wr into M[n][oc][p] (p=h*16+kc):
//   out = M @ softmax_dk(q) + br.
// All projections via mfma_f32_16x16x32_f16, single-term (fp16 operand
// rounding 2^-11; fp32 accumulate). Hardware v_cvt for all conversions.

#define NTOK 262144
typedef float4 f4;
typedef _Float16 f16;
typedef __attribute__((ext_vector_type(8))) _Float16 f16x8;
typedef __attribute__((ext_vector_type(4))) _Float16 f16x4;
typedef __attribute__((ext_vector_type(4))) float f32x4;

// ---- workspace float offsets ----
#define WS_S  0      // 2048 : S[n][h][kc][vc] f32
#define WS_Z  2048   // 128  : Z[n][h*16+kc]   f32
#define WS_MH 2176   // 4096 floats = 8192 f16 : M[n][c][p] f16

__device__ __forceinline__ f16x8 cvt8h(const float* v) {
    f16x8 r;
    #pragma unroll
    for (int m = 0; m < 8; ++m) r[m] = (f16)v[m];
    return r;
}

__global__ __launch_bounds__(256) void k_init(float* __restrict__ ws) {
    int i = blockIdx.x * 256 + threadIdx.x;
    if (i < 2176) ws[i] = 0.0f;   // zero S and Z
}

// ---------------- Pass 1: k,v projection + ctx accumulation ----------------
// Wave w = head w. A-frag = x rows (token=lane&15, j=8*(lane>>4)+m+32jc),
// B-frag = Wk/Wv rows (c=16w+(lane&15)) -> D[t][c]: lane holds col c=lane&15,
// rows t=4*(lane>>4)+r. Phase C per 32 tokens: S += EK^T x EV via LDS repack.
__global__ __launch_bounds__(256) void k_ctx(const float* __restrict__ x,
                                             const float* __restrict__ Wk,
                                             const float* __restrict__ bk,
                                             const float* __restrict__ Wv,
                                             const float* __restrict__ bv,
                                             float* __restrict__ ws) {
    __shared__ f16 ekb[4][16][40];   // per-wave [c][t], stride 40 (16B-aligned rows)
    __shared__ f16 evb[4][16][40];

    const int tid  = threadIdx.x;
    const int w    = tid >> 6;
    const int lane = tid & 63;
    const int lr   = lane & 15;
    const int ql   = lane >> 4;

    const int nb = blockIdx.x >> 9;
    const int bi = blockIdx.x & 511;
    const long base = (long)nb * NTOK + (long)bi * 512;

    // W B-frags (f16, register-resident): lane holds c=16w+lr, k=j=32jc+8ql+m
    f16x8 wkf[2], wvf[2];
    {
        const float* wkrow = &Wk[(16 * w + lr) * 64 + 8 * ql];
        const float* wvrow = &Wv[(16 * w + lr) * 64 + 8 * ql];
        float t[8];
        #pragma unroll
        for (int jc = 0; jc < 2; ++jc) {
            *(f4*)&t[0] = *(const f4*)&wkrow[32 * jc];
            *(f4*)&t[4] = *(const f4*)&wkrow[32 * jc + 4];
            wkf[jc] = cvt8h(t);
            *(f4*)&t[0] = *(const f4*)&wvrow[32 * jc];
            *(f4*)&t[4] = *(const f4*)&wvrow[32 * jc + 4];
            wvf[jc] = cvt8h(t);
        }
    }
    const float bks = bk[16 * w + lr];
    const float bvs = bv[16 * w + lr];

    const f32x4 zero4 = {0.f, 0.f, 0.f, 0.f};
    f32x4 S = zero4;
    float z = 0.f;

    for (int ch = 0; ch < 16; ++ch) {
        #pragma unroll
        for (int s = 0; s < 2; ++s) {
            const float* xp = x + (((size_t)(base + ch * 32 + s * 16 + lr)) << 6) + 8 * ql;
            float t0[8], t1[8];
            *(f4*)&t0[0] = *(const f4*)(xp);
            *(f4*)&t0[4] = *(const f4*)(xp + 4);
            *(f4*)&t1[0] = *(const f4*)(xp + 32);
            *(f4*)&t1[4] = *(const f4*)(xp + 36);
            f16x8 a0 = cvt8h(t0), a1 = cvt8h(t1);
            f32x4 ak = zero4, av = zero4;
            ak = __builtin_amdgcn_mfma_f32_16x16x32_f16(a0, wkf[0], ak, 0, 0, 0);
            ak = __builtin_amdgcn_mfma_f32_16x16x32_f16(a1, wkf[1], ak, 0, 0, 0);
            av = __builtin_amdgcn_mfma_f32_16x16x32_f16(a0, wvf[0], av, 0, 0, 0);
            av = __builtin_amdgcn_mfma_f32_16x16x32_f16(a1, wvf[1], av, 0, 0, 0);
            const float e0 = __expf(ak[0] + bks), e1 = __expf(ak[1] + bks);
            const float e2 = __expf(ak[2] + bks), e3 = __expf(ak[3] + bks);
            z += (e0 + e1) + (e2 + e3);
            f16x4 pk = {(f16)e0, (f16)e1, (f16)e2, (f16)e3};
            f16x4 pv = {(f16)(av[0] + bvs), (f16)(av[1] + bvs),
                        (f16)(av[2] + bvs), (f16)(av[3] + bvs)};
            *(f16x4*)&ekb[w][lr][s * 16 + 4 * ql] = pk;   // [c=lr][t=16s+4ql..+3]
            *(f16x4*)&evb[w][lr][s * 16 + 4 * ql] = pv;
        }
        // phase C: A = EK^T (row kc=lr, k=t=8ql+m), B = EV (col vc=lr, same t)
        f16x8 ekf = *(f16x8*)&ekb[w][lr][8 * ql];
        f16x8 evf = *(f16x8*)&evb[w][lr][8 * ql];
        S = __builtin_amdgcn_mfma_f32_16x16x32_f16(ekf, evf, S, 0, 0, 0);
    }

    // z: same kc=lr lives on lanes lr, lr+16, lr+32, lr+48
    z += __shfl_xor(z, 16);
    z += __shfl_xor(z, 32);
    // S D-layout: col vc=lr, row kc=4ql+r
    float* Sp = ws + WS_S + nb * 1024 + w * 256;
    #pragma unroll
    for (int r = 0; r < 4; ++r)
        atomicAdd(&Sp[(4 * ql + r) * 16 + lr], S[r]);
    if (lane < 16)
        atomicAdd(&ws[WS_Z + nb * 64 + w * 16 + lane], z);
}

// ---------------- M = Wr @ (S/Z) fold : M[n][c][p] in fp16 ----------------
__global__ __launch_bounds__(256) void k_m(const float* __restrict__ Wr,
                                           float* __restrict__ ws) {
    const int n = blockIdx.x;
    f16* MH = (f16*)(ws + WS_MH);
    for (int i = threadIdx.x; i < 4096; i += 256) {
        const int c = i >> 6, p = i & 63;
        const int h = p >> 4, kc = p & 15;
        const float rz = 1.0f / ws[WS_Z + n * 64 + p];
        const float* Srow = ws + WS_S + n * 1024 + h * 256 + kc * 16;
        const float* Wrow = Wr + c * 64 + h * 16;
        float acc = 0.f;
        #pragma unroll
        for (int vc = 0; vc < 16; ++vc) acc += Wrow[vc] * Srow[vc];
        MH[n * 4096 + c * 64 + p] = (f16)(acc * rz);
    }
}

// ---------------- Pass 2: q proj + softmax + M apply (fp16) ----------------
// Wave w = head w for q, oc-tile w for out. 128 tokens/block.
// Phase A: D_q[c][t] = Wq(A) x X^T(B); softmax over c (regs + shfl 16/32);
//          qhat f16 -> LDS [t][p] (stride 72, XOR-swizzled by (row&3)<<4).
// Phase B: D_out[oc][t] = M(A) x qhat(B), + br, store.
__global__ __launch_bounds__(256) void k_out(const float* __restrict__ x,
                                             const float* __restrict__ Wq,
                                             const float* __restrict__ bq,
                                             const float* __restrict__ br,
                                             float* __restrict__ out,
                                             const float* __restrict__ ws) {
    __shared__ f16 qh[128][72];

    const int tid  = threadIdx.x;
    const int w    = tid >> 6;
    const int lane = tid & 63;
    const int lr   = lane & 15;
    const int ql   = lane >> 4;

    const int nb = blockIdx.x >> 11;
    const int bi = blockIdx.x & 2047;
    const long base = (long)nb * NTOK + (long)bi * 128;

    // Wq A-frags: lane row c(within head)=lr -> Wq[16w+lr][32jc+8ql+m]
    f16x8 wqf[2];
    {
        const float* wr = &Wq[(16 * w + lr) * 64 + 8 * ql];
        float t[8];
        #pragma unroll
        for (int jc = 0; jc < 2; ++jc) {
            *(f4*)&t[0] = *(const f4*)&wr[32 * jc];
            *(f4*)&t[4] = *(const f4*)&wr[32 * jc + 4];
            wqf[jc] = cvt8h(t);
        }
    }
    // M A-frags (precomputed f16): lane row oc=16w+lr, k=p=32pc+8ql+m
    f16x8 mf[2];
    {
        const f16* mrow = (const f16*)(ws + WS_MH) + nb * 4096 + (16 * w + lr) * 64 + 8 * ql;
        #pragma unroll
        for (int pc = 0; pc < 2; ++pc)
            mf[pc] = *(const f16x8*)&mrow[32 * pc];
    }
    const f4 bq4 = *(const f4*)&bq[16 * w + 4 * ql];
    const f4 br4 = *(const f4*)&br[16 * w + 4 * ql];
    const f32x4 zero4 = {0.f, 0.f, 0.f, 0.f};

    // ---- phase A ----
    for (int s = 0; s < 8; ++s) {
        const float* xp = x + (((size_t)(base + s * 16 + lr)) << 6) + 8 * ql;
        float t0[8], t1[8];
        *(f4*)&t0[0] = *(const f4*)(xp);
        *(f4*)&t0[4] = *(const f4*)(xp + 4);
        *(f4*)&t1[0] = *(const f4*)(xp + 32);
        *(f4*)&t1[4] = *(const f4*)(xp + 36);
        f16x8 b0 = cvt8h(t0), b1 = cvt8h(t1);
        f32x4 aq = zero4;
        aq = __builtin_amdgcn_mfma_f32_16x16x32_f16(wqf[0], b0, aq, 0, 0, 0);
        aq = __builtin_amdgcn_mfma_f32_16x16x32_f16(wqf[1], b1, aq, 0, 0, 0);
        // softmax over head channels c = 4ql+r (regs) x quartiles (shfl)
        float q0 = aq[0] + bq4.x, q1 = aq[1] + bq4.y;
        float q2 = aq[2] + bq4.z, q3 = aq[3] + bq4.w;
        float mx = fmaxf(fmaxf(q0, q1), fmaxf(q2, q3));
        mx = fmaxf(mx, __shfl_xor(mx, 16));
        mx = fmaxf(mx, __shfl_xor(mx, 32));
        float e0 = __expf(q0 - mx), e1 = __expf(q1 - mx);
        float e2 = __expf(q2 - mx), e3 = __expf(q3 - mx);
        float sm = (e0 + e1) + (e2 + e3);
        sm += __shfl_xor(sm, 16);
        sm += __shfl_xor(sm, 32);
        const float rs = 1.0f / sm;
        // f16 + swizzled write: row = token, real col p = 16w+4ql+r,
        // stored col = real ^ ((row&3)<<4)
        const int row = s * 16 + lr;
        const int cb  = (16 * (w ^ (row & 3))) + 4 * ql;
        f16x4 ph = {(f16)(e0 * rs), (f16)(e1 * rs), (f16)(e2 * rs), (f16)(e3 * rs)};
        *(f16x4*)&qh[row][cb] = ph;
    }
    __syncthreads();
    // ---- phase B ----
    for (int s = 0; s < 8; ++s) {
        const int row = s * 16 + lr;                 // token = col t of D_out
        f32x4 o = zero4;
        #pragma unroll
        for (int pc = 0; pc < 2; ++pc) {
            const int cb = (32 * pc + 8 * ql) ^ ((row & 3) << 4);
            f16x8 qv = *(f16x8*)&qh[row][cb];
            o = __builtin_amdgcn_mfma_f32_16x16x32_f16(mf[pc], qv, o, 0, 0, 0);
        }
        const f4 res = {o[0] + br4.x, o[1] + br4.y, o[2] + br4.z, o[3] + br4.w};
        *(f4*)&out[(((size_t)(base + s * 16 + lr)) << 6) + 16 * w + 4 * ql] = res;
    }
}

extern "C" void kernel_launch(void* const* d_in, const int* in_sizes, int n_in,
                              void* d_out, int out_size, void* d_ws, size_t ws_size,
                              hipStream_t stream) {
    const float* x  = (const float*)d_in[0];
    const float* Wk = (const float*)d_in[1];
    const float* bk = (const float*)d_in[2];
    const float* Wq = (const float*)d_in[3];
    const float* bq = (const float*)d_in[4];
    const float* Wv = (const float*)d_in[5];
    const float* bv = (const float*)d_in[6];
    const float* Wr = (const float*)d_in[7];
    const float* br = (const float*)d_in[8];
    float* out = (float*)d_out;
    float* ws  = (float*)d_ws;

    hipLaunchKernelGGL(k_init, dim3(9),    dim3(256), 0, stream, ws);
    hipLaunchKernelGGL(k_ctx,  dim3(1024), dim3(256), 0, stream, x, Wk, bk, Wv, bv, ws);
    hipLaunchKernelGGL(k_m,    dim3(2),    dim3(256), 0, stream, Wr, ws);
    hipLaunchKernelGGL(k_out,  dim3(4096), dim3(256), 0, stream, x, Wq, bq, br, out, ws);
}

// Round 5
// 124.776 us; speedup vs baseline: 3.2289x; 1.3330x over previous
//
#include <hip/hip_runtime.h>
#include <math.h>

// EfficientAttention, fp16-MFMA, wave-owns-tokens version.
//   ctx_h = softmax_N(k_h) @ v_h^T folded with Wr into M[n][oc][p] (p=h*16+kc):
//   out = M @ softmax_dk(q) + br.
// Each wave processes its own disjoint token range for ALL heads (weights for
// all 4 heads register-resident) -> no cross-wave load redundancy.

#define NTOK 262144
typedef float4 f4;
typedef _Float16 f16;
typedef __attribute__((ext_vector_type(8))) _Float16 f16x8;
typedef __attribute__((ext_vector_type(4))) _Float16 f16x4;
typedef __attribute__((ext_vector_type(4))) float f32x4;

// ---- workspace float offsets ----
#define WS_S  0      // 2048 : S[n][h][kc][vc] f32
#define WS_Z  2048   // 128  : Z[n][h*16+kc]   f32
#define WS_MH 2176   // 4096 floats = 8192 f16 : M[n][c][p] f16

__device__ __forceinline__ f16x8 cvt8h2(f4 a, f4 b) {
    f16x8 r;
    r[0] = (f16)a.x; r[1] = (f16)a.y; r[2] = (f16)a.z; r[3] = (f16)a.w;
    r[4] = (f16)b.x; r[5] = (f16)b.y; r[6] = (f16)b.z; r[7] = (f16)b.w;
    return r;
}

__global__ __launch_bounds__(256) void k_init(float* __restrict__ ws) {
    int i = blockIdx.x * 256 + threadIdx.x;
    if (i < 2176) ws[i] = 0.0f;   // zero S and Z
}

// ---------------- Pass 1: k,v projection + ctx accumulation ----------------
// Wave w owns tokens [w*128, w*128+128) of the block's 512, computes all heads.
// A-frag = x rows (token=lane&15, j=8*(lane>>4)+m+32jc); B-frag = Wk/Wv rows
// (c=16h+(lane&15)) -> D[t][c]: lane holds col c=lane&15, rows t=4(lane>>4)+r.
// Phase C per 32 tokens per head: S_h += EK_h^T x EV_h via per-(wave,head)
// LDS repack (in-wave, no barriers). S/Z block-reduced in LDS, then atomics.
__global__ __launch_bounds__(256) void k_ctx(const float* __restrict__ x,
                                             const float* __restrict__ Wk,
                                             const float* __restrict__ bk,
                                             const float* __restrict__ Wv,
                                             const float* __restrict__ bv,
                                             float* __restrict__ ws) {
    __shared__ __align__(16) char smem[40960];
    f16 (*ekb)[16][40] = (f16(*)[16][40])smem;             // [w*4+h][c][t]
    f16 (*evb)[16][40] = (f16(*)[16][40])(smem + 20480);

    const int tid  = threadIdx.x;
    const int w    = tid >> 6;
    const int lane = tid & 63;
    const int lr   = lane & 15;
    const int ql   = lane >> 4;

    const int nb = blockIdx.x >> 9;
    const int bi = blockIdx.x & 511;
    const long base = (long)nb * NTOK + (long)bi * 512 + (long)w * 128;

    // B-frags for all heads (f16, register-resident): lane c=16h+lr, k=32jc+8ql+m
    f16x8 wkf[4][2], wvf[4][2];
    float bks[4], bvs[4];
    #pragma unroll
    for (int h = 0; h < 4; ++h) {
        const float* kr = &Wk[(16 * h + lr) * 64 + 8 * ql];
        const float* vr = &Wv[(16 * h + lr) * 64 + 8 * ql];
        #pragma unroll
        for (int jc = 0; jc < 2; ++jc) {
            wkf[h][jc] = cvt8h2(*(const f4*)&kr[32 * jc], *(const f4*)&kr[32 * jc + 4]);
            wvf[h][jc] = cvt8h2(*(const f4*)&vr[32 * jc], *(const f4*)&vr[32 * jc + 4]);
        }
        bks[h] = bk[16 * h + lr];
        bvs[h] = bv[16 * h + lr];
    }

    const f32x4 zero4 = {0.f, 0.f, 0.f, 0.f};
    f32x4 S[4] = {zero4, zero4, zero4, zero4};
    float z[4] = {0.f, 0.f, 0.f, 0.f};

    // prefetch subtile 0
    f4 L0, L1, L2, L3;
    {
        const float* xp = x + (((size_t)(base + lr)) << 6) + 8 * ql;
        L0 = *(const f4*)xp;        L1 = *(const f4*)(xp + 4);
        L2 = *(const f4*)(xp + 32); L3 = *(const f4*)(xp + 36);
    }

    for (int ch = 0; ch < 4; ++ch) {          // 4 chunks of 32 tokens
        #pragma unroll
        for (int s = 0; s < 2; ++s) {         // 2 subtiles of 16
            f16x8 a0 = cvt8h2(L0, L1), a1 = cvt8h2(L2, L3);
            const int nxt = ch * 2 + s + 1;
            if (nxt < 8) {                    // prefetch next subtile
                const float* xp = x + (((size_t)(base + nxt * 16 + lr)) << 6) + 8 * ql;
                L0 = *(const f4*)xp;        L1 = *(const f4*)(xp + 4);
                L2 = *(const f4*)(xp + 32); L3 = *(const f4*)(xp + 36);
            }
            #pragma unroll
            for (int h = 0; h < 4; ++h) {
                f32x4 ak = zero4, av = zero4;
                ak = __builtin_amdgcn_mfma_f32_16x16x32_f16(a0, wkf[h][0], ak, 0, 0, 0);
                ak = __builtin_amdgcn_mfma_f32_16x16x32_f16(a1, wkf[h][1], ak, 0, 0, 0);
                av = __builtin_amdgcn_mfma_f32_16x16x32_f16(a0, wvf[h][0], av, 0, 0, 0);
                av = __builtin_amdgcn_mfma_f32_16x16x32_f16(a1, wvf[h][1], av, 0, 0, 0);
                const float e0 = __expf(ak[0] + bks[h]), e1 = __expf(ak[1] + bks[h]);
                const float e2 = __expf(ak[2] + bks[h]), e3 = __expf(ak[3] + bks[h]);
                z[h] += (e0 + e1) + (e2 + e3);
                f16x4 pk = {(f16)e0, (f16)e1, (f16)e2, (f16)e3};
                f16x4 pv = {(f16)(av[0] + bvs[h]), (f16)(av[1] + bvs[h]),
                            (f16)(av[2] + bvs[h]), (f16)(av[3] + bvs[h])};
                *(f16x4*)&ekb[w * 4 + h][lr][s * 16 + 4 * ql] = pk;
                *(f16x4*)&evb[w * 4 + h][lr][s * 16 + 4 * ql] = pv;
            }
        }
        #pragma unroll
        for (int h = 0; h < 4; ++h) {
            f16x8 ekf = *(f16x8*)&ekb[w * 4 + h][lr][8 * ql];
            f16x8 evf = *(f16x8*)&evb[w * 4 + h][lr][8 * ql];
            S[h] = __builtin_amdgcn_mfma_f32_16x16x32_f16(ekf, evf, S[h], 0, 0, 0);
        }
    }

    // z: quartile lanes (lr, lr+16, lr+32, lr+48) hold same kc=lr
    #pragma unroll
    for (int h = 0; h < 4; ++h) {
        z[h] += __shfl_xor(z[h], 16);
        z[h] += __shfl_xor(z[h], 32);
    }

    // block-level reduction of S,z in LDS (reuse repack memory), then atomics
    __syncthreads();
    float* sr = (float*)smem;              // [w][h][kc][vc] : 16 KB
    float* zr = (float*)(smem + 16384);    // [w][h][kc]     : 1 KB
    #pragma unroll
    for (int h = 0; h < 4; ++h) {
        #pragma unroll
        for (int r = 0; r < 4; ++r)
            sr[((w * 4 + h) * 16 + 4 * ql + r) * 16 + lr] = S[h][r];
        if (lane < 16) zr[(w * 4 + h) * 16 + lane] = z[h];
    }
    __syncthreads();
    #pragma unroll
    for (int i = 0; i < 4; ++i) {
        const int idx = i * 256 + tid;     // h=i, kc=tid>>4, vc=tid&15
        const float acc = sr[idx] + sr[1024 + idx] + sr[2048 + idx] + sr[3072 + idx];
        atomicAdd(&ws[WS_S + nb * 1024 + idx], acc);
    }
    if (tid < 64) {
        const float acc = zr[tid] + zr[64 + tid] + zr[128 + tid] + zr[192 + tid];
        atomicAdd(&ws[WS_Z + nb * 64 + tid], acc);
    }
}

// ---------------- M = Wr @ (S/Z) fold : M[n][c][p] in fp16 ----------------
__global__ __launch_bounds__(256) void k_m(const float* __restrict__ Wr,
                                           float* __restrict__ ws) {
    const int n = blockIdx.x;
    f16* MH = (f16*)(ws + WS_MH);
    for (int i = threadIdx.x; i < 4096; i += 256) {
        const int c = i >> 6, p = i & 63;
        const int h = p >> 4, kc = p & 15;
        const float rz = 1.0f / ws[WS_Z + n * 64 + p];
        const float* Srow = ws + WS_S + n * 1024 + h * 256 + kc * 16;
        const float* Wrow = Wr + c * 64 + h * 16;
        float acc = 0.f;
        #pragma unroll
        for (int vc = 0; vc < 16; ++vc) acc += Wrow[vc] * Srow[vc];
        MH[n * 4096 + c * 64 + p] = (f16)(acc * rz);
    }
}

// ---------------- Pass 2: q proj + softmax + M apply (fp16) ----------------
// Wave w owns tokens [w*64, w*64+64) of the block's 256; all heads/oc-tiles.
// Per 16-token subtile: q proj (Wq A x X^T B), per-head softmax (regs+shfl),
// qhat -> per-wave LDS [t][p] (stride 72, XOR swizzle (lr&3)<<4), then
// out = M(A) x qhat(B) + br. No __syncthreads anywhere.
__global__ __launch_bounds__(256) void k_out(const float* __restrict__ x,
                                             const float* __restrict__ Wq,
                                             const float* __restrict__ bq,
                                             const float* __restrict__ br,
                                             float* __restrict__ out,
                                             const float* __restrict__ ws) {
    __shared__ f16 qb[4][16][72];

    const int tid  = threadIdx.x;
    const int w    = tid >> 6;
    const int lane = tid & 63;
    const int lr   = lane & 15;
    const int ql   = lane >> 4;

    const int nb = blockIdx.x >> 10;
    const int bi = blockIdx.x & 1023;
    const long base = (long)nb * NTOK + (long)bi * 256 + (long)w * 64;

    // Wq A-frags for all heads: lane row c(within head)=lr, k=32jc+8ql+m
    f16x8 wqf[4][2];
    f4 bqv[4];
    #pragma unroll
    for (int h = 0; h < 4; ++h) {
        const float* qr = &Wq[(16 * h + lr) * 64 + 8 * ql];
        #pragma unroll
        for (int jc = 0; jc < 2; ++jc)
            wqf[h][jc] = cvt8h2(*(const f4*)&qr[32 * jc], *(const f4*)&qr[32 * jc + 4]);
        bqv[h] = *(const f4*)&bq[16 * h + 4 * ql];
    }
    // M A-frags for all oc-tiles (precomputed f16): lane row oc=16*oct+lr, k=p
    f16x8 mf[4][2];
    f4 brv[4];
    const f16* MH = (const f16*)(ws + WS_MH) + (size_t)nb * 4096;
    #pragma unroll
    for (int oc = 0; oc < 4; ++oc) {
        #pragma unroll
        for (int pc = 0; pc < 2; ++pc)
            mf[oc][pc] = *(const f16x8*)&MH[(16 * oc + lr) * 64 + 32 * pc + 8 * ql];
        brv[oc] = *(const f4*)&br[16 * oc + 4 * ql];
    }

    const f32x4 zero4 = {0.f, 0.f, 0.f, 0.f};
    const int sw = (lr & 3) << 4;

    // prefetch subtile 0
    f4 L0, L1, L2, L3;
    {
        const float* xp = x + (((size_t)(base + lr)) << 6) + 8 * ql;
        L0 = *(const f4*)xp;        L1 = *(const f4*)(xp + 4);
        L2 = *(const f4*)(xp + 32); L3 = *(const f4*)(xp + 36);
    }

    for (int s = 0; s < 4; ++s) {
        f16x8 b0 = cvt8h2(L0, L1), b1 = cvt8h2(L2, L3);
        if (s < 3) {
            const float* xp = x + (((size_t)(base + (s + 1) * 16 + lr)) << 6) + 8 * ql;
            L0 = *(const f4*)xp;        L1 = *(const f4*)(xp + 4);
            L2 = *(const f4*)(xp + 32); L3 = *(const f4*)(xp + 36);
        }
        // phase A: q projection + per-head softmax over c
        #pragma unroll
        for (int h = 0; h < 4; ++h) {
            f32x4 aq = zero4;
            aq = __builtin_amdgcn_mfma_f32_16x16x32_f16(wqf[h][0], b0, aq, 0, 0, 0);
            aq = __builtin_amdgcn_mfma_f32_16x16x32_f16(wqf[h][1], b1, aq, 0, 0, 0);
            float q0 = aq[0] + bqv[h].x, q1 = aq[1] + bqv[h].y;
            float q2 = aq[2] + bqv[h].z, q3 = aq[3] + bqv[h].w;
            float mx = fmaxf(fmaxf(q0, q1), fmaxf(q2, q3));
            mx = fmaxf(mx, __shfl_xor(mx, 16));
            mx = fmaxf(mx, __shfl_xor(mx, 32));
            float e0 = __expf(q0 - mx), e1 = __expf(q1 - mx);
            float e2 = __expf(q2 - mx), e3 = __expf(q3 - mx);
            float sm = (e0 + e1) + (e2 + e3);
            sm += __shfl_xor(sm, 16);
            sm += __shfl_xor(sm, 32);
            const float rs = 1.0f / sm;
            f16x4 ph = {(f16)(e0 * rs), (f16)(e1 * rs), (f16)(e2 * rs), (f16)(e3 * rs)};
            *(f16x4*)&qb[w][lr][16 * (h ^ (lr & 3)) + 4 * ql] = ph;
        }
        // phase B: out = M x qhat + br (in-wave LDS dependency, no barrier)
        f16x8 qv0 = *(f16x8*)&qb[w][lr][(8 * ql) ^ sw];
        f16x8 qv1 = *(f16x8*)&qb[w][lr][(32 + 8 * ql) ^ sw];
        const size_t obase = ((size_t)(base + s * 16 + lr)) << 6;
        #pragma unroll
        for (int oc = 0; oc < 4; ++oc) {
            f32x4 o = zero4;
            o = __builtin_amdgcn_mfma_f32_16x16x32_f16(mf[oc][0], qv0, o, 0, 0, 0);
            o = __builtin_amdgcn_mfma_f32_16x16x32_f16(mf[oc][1], qv1, o, 0, 0, 0);
            const f4 res = {o[0] + brv[oc].x, o[1] + brv[oc].y,
                            o[2] + brv[oc].z, o[3] + brv[oc].w};
            *(f4*)&out[obase + 16 * oc + 4 * ql] = res;
        }
    }
}

extern "C" void kernel_launch(void* const* d_in, const int* in_sizes, int n_in,
                              void* d_out, int out_size, void* d_ws, size_t ws_size,
                              hipStream_t stream) {
    const float* x  = (const float*)d_in[0];
    const float* Wk = (const float*)d_in[1];
    const float* bk = (const float*)d_in[2];
    const float* Wq = (const float*)d_in[3];
    const float* bq = (const float*)d_in[4];
    const float* Wv = (const float*)d_in[5];
    const float* bv = (const float*)d_in[6];
    const float* Wr = (const float*)d_in[7];
    const float* br = (const float*)d_in[8];
    float* out = (float*)d_out;
    float* ws  = (float*)d_ws;

    hipLaunchKernelGGL(k_init, dim3(9),    dim3(256), 0, stream, ws);
    hipLaunchKernelGGL(k_ctx,  dim3(1024), dim3(256), 0, stream, x, Wk, bk, Wv, bv, ws);
    hipLaunchKernelGGL(k_m,    dim3(2),    dim3(256), 0, stream, Wr, ws);
    hipLaunchKernelGGL(k_out,  dim3(2048), dim3(256), 0, stream, x, Wq, bq, br, out, ws);
}